// Round 8
// baseline (379.794 us; speedup 1.0000x reference)
//
#include <hip/hip_runtime.h>
#include <hip/hip_bf16.h>

#define N_NODES 50000
#define NNZ 800000
#define F 256
#define L_OPS 4
#define ELL_C 64     // max row degree; Poisson(16) => P(deg>=64) ~ 1e-19 per row
#define RTILES 3125  // 50000 / 16 row tiles
#define NBK 98       // buckets of 512 rows
#define CHUNK 4096
#define CHUNKS 196   // ceil(NNZ / 4096)
#define N32 (N_NODES * 32)  // bytes per H slice

typedef unsigned int uint;
typedef unsigned short u16;
typedef unsigned char u8;
typedef unsigned long long u64;
typedef __attribute__((ext_vector_type(8))) short bf16x8;
typedef __attribute__((ext_vector_type(4))) float f32x4;
typedef __attribute__((ext_vector_type(2))) float f32x2;

#if defined(__has_builtin)
#if __has_builtin(__builtin_amdgcn_cvt_pk_f32_fp8) && \
    __has_builtin(__builtin_amdgcn_cvt_pk_fp8_f32)
#define HAS_FP8_CVT 1
#endif
#endif

__device__ inline u16 f2bf(float f) {
  return __bfloat16_as_ushort(__float2bfloat16(f));  // hw v_cvt (RNE)
}
__device__ inline float shrinkf(float f) {
  float t = fabsf(f) - 1e-4f;
  t = t > 0.f ? t : 0.f;
  return copysignf(t, f);
}

// ---- fp8 e4m3 (OCP) helpers ----
__device__ inline uint fp8_enc1(float f) {
#ifdef HAS_FP8_CVT
  return (uint)__builtin_amdgcn_cvt_pk_fp8_f32(f, 0.f, 0, false) & 0xFFu;
#else
  float y = f * 0x1.0p-120f;
  uint b = __float_as_uint(y);
  uint s = (b >> 24) & 0x80u;
  b &= 0x7FFFFFFFu;
  uint r = b + 0x7FFFFu + ((b >> 20) & 1u);
  return s | ((r >> 20) & 0x7Fu);
#endif
}
__device__ inline uint fp8_enc4(float a, float b, float c, float d) {
#ifdef HAS_FP8_CVT
  uint w = (uint)__builtin_amdgcn_cvt_pk_fp8_f32(a, b, 0, false);
  w = (uint)__builtin_amdgcn_cvt_pk_fp8_f32(c, d, w, true);
  return w;
#else
  return fp8_enc1(a) | (fp8_enc1(b) << 8) | (fp8_enc1(c) << 16) |
         (fp8_enc1(d) << 24);
#endif
}
__device__ inline float fp8_dec1(uint b) {
  uint u = ((b & 0x80u) << 24) | ((b & 0x7Fu) << 20);
  return __uint_as_float(u) * 0x1.0p+120f;
}

// ---------------- W prep ----------------
__global__ __launch_bounds__(256) void wprep_k(const float* __restrict__ W,
                                               u16* __restrict__ Wb) {
  int T = blockIdx.x * 256 + threadIdx.x;
  if (T >= 16 * 8 * 64) return;
  int lane = T & 63;
  int ks = (T >> 6) & 7;
  int ct = T >> 9;
  int k0 = ks * 32 + (lane >> 4) * 8;
  int n = ct * 16 + (lane & 15);
  u16* o = Wb + (size_t)T * 8;
#pragma unroll
  for (int j = 0; j < 8; ++j) o[j] = f2bf(W[(size_t)(k0 + j) * F + n]);
}

// -------- GEMM: H(fp8 sliced layout, scale 2^4) = X @ W via MFMA --------
__global__ __launch_bounds__(256) void gemm_mfma(const float* __restrict__ X,
                                                 const u16* __restrict__ Wb,
                                                 u8* __restrict__ H) {
  const int w = threadIdx.x >> 6, lane = threadIdx.x & 63;
  const int lr = lane & 15, kg = lane >> 4;
  const int ct0 = w * 4;

  bf16x8 b[4][8];
#pragma unroll
  for (int c = 0; c < 4; ++c)
#pragma unroll
    for (int ks = 0; ks < 8; ++ks)
      b[c][ks] = *(const bf16x8*)(Wb + ((size_t)((ct0 + c) * 8 + ks) * 64 + lane) * 8);

  for (int tile = blockIdx.x; tile < RTILES; tile += gridDim.x) {
    const int rb = tile * 16;
    const float* xp = X + (size_t)(rb + lr) * F + kg * 8;
    f32x4 acc[4];
#pragma unroll
    for (int c = 0; c < 4; ++c) acc[c] = (f32x4){0.f, 0.f, 0.f, 0.f};
#pragma unroll
    for (int ks = 0; ks < 8; ++ks) {
      float4 x0 = *(const float4*)(xp + ks * 32);
      float4 x1 = *(const float4*)(xp + ks * 32 + 4);
      bf16x8 a;
      a[0] = (short)f2bf(x0.x); a[1] = (short)f2bf(x0.y);
      a[2] = (short)f2bf(x0.z); a[3] = (short)f2bf(x0.w);
      a[4] = (short)f2bf(x1.x); a[5] = (short)f2bf(x1.y);
      a[6] = (short)f2bf(x1.z); a[7] = (short)f2bf(x1.w);
#pragma unroll
      for (int c = 0; c < 4; ++c)
        acc[c] = __builtin_amdgcn_mfma_f32_16x16x32_bf16(a, b[c][ks], acc[c], 0, 0, 0);
    }
    const int r0 = rb + kg * 4;
#pragma unroll
    for (int c = 0; c < 4; ++c) {
      const int col = (ct0 + c) * 16 + lr;
      const int slice = col >> 5, within = col & 31;
#pragma unroll
      for (int reg = 0; reg < 4; ++reg)
        H[(size_t)slice * N32 + (size_t)(r0 + reg) * 32 + within] =
            (u8)fp8_enc1(acc[c][reg] * 16.f);
    }
  }
}

// ============ ELL build via radix buckets — NO global atomics ============
// B1: per-chunk LDS histogram over NBK buckets (512 rows each)
__global__ __launch_bounds__(256) void b1_hist(const int* __restrict__ rows,
                                               int* __restrict__ hoff) {
  const int op = blockIdx.y, c = blockIdx.x;
  __shared__ int h[NBK];
  for (int t = threadIdx.x; t < NBK; t += 256) h[t] = 0;
  __syncthreads();
  const int* rop = rows + (size_t)op * NNZ;
  const int base = c * CHUNK + threadIdx.x;
#pragma unroll
  for (int it = 0; it < 16; ++it) {
    int i = base + it * 256;
    if (i < NNZ) atomicAdd(&h[rop[i] >> 9], 1);
  }
  __syncthreads();
  for (int t = threadIdx.x; t < NBK; t += 256)
    hoff[((size_t)op * CHUNKS + c) * NBK + t] = h[t];
}

// B2a: per (op,bucket): exclusive scan over chunks (in place) + bucket total
__global__ __launch_bounds__(512) void b2a_scan(int* __restrict__ hoff,
                                                int* __restrict__ tot) {
  const int op = blockIdx.y, b = blockIdx.x, t = threadIdx.x;
  __shared__ int sh[512];
  int v = (t < CHUNKS) ? hoff[((size_t)op * CHUNKS + t) * NBK + b] : 0;
  sh[t] = v;
  __syncthreads();
#pragma unroll
  for (int off = 1; off < 512; off <<= 1) {
    int tmp = (t >= off) ? sh[t - off] : 0;
    __syncthreads();
    sh[t] += tmp;
    __syncthreads();
  }
  if (t < CHUNKS) hoff[((size_t)op * CHUNKS + t) * NBK + b] = sh[t] - v;
  if (t == 511) tot[op * NBK + b] = sh[511];
}

// B2b: per op: exclusive scan of bucket totals -> bases
__global__ __launch_bounds__(128) void b2b_base(const int* __restrict__ tot,
                                                int* __restrict__ bs) {
  const int op = blockIdx.x, t = threadIdx.x;
  __shared__ int sh[128];
  int v = (t < NBK) ? tot[op * NBK + t] : 0;
  sh[t] = v;
  __syncthreads();
#pragma unroll
  for (int off = 1; off < 128; off <<= 1) {
    int tmp = (t >= off) ? sh[t - off] : 0;
    __syncthreads();
    sh[t] += tmp;
    __syncthreads();
  }
  if (t < NBK) bs[op * NBK + t] = sh[t] - v;
}

// B3: in-LDS counting sort per 4096-chunk, then coalesced sequential write-out.
// packed item: cv(32) | bucket(7, bits 9-15) | row_local(9, bits 0-8)
__global__ __launch_bounds__(256) void b3_scatter(const int* __restrict__ rows,
                                                  const int* __restrict__ cols,
                                                  const float* __restrict__ vals,
                                                  const int* __restrict__ hoff,
                                                  const int* __restrict__ bs,
                                                  u64* __restrict__ part) {
  const int op = blockIdx.y, c = blockIdx.x;
  __shared__ int hist[NBK];
  __shared__ int lstart[NBK];
  __shared__ int gbase[NBK];
  __shared__ int cur[NBK];
  __shared__ int sh[256];
  __shared__ u64 stage[CHUNK];
  const int t = threadIdx.x;
  for (int k = t; k < NBK; k += 256) hist[k] = 0;
  __syncthreads();
  const int* rop = rows + (size_t)op * NNZ;
  const int* cop = cols + (size_t)op * NNZ;
  const float* vop = vals + (size_t)op * NNZ;
  const int n0 = c * CHUNK;
  const int nthis = min(CHUNK, NNZ - n0);
  // pass 1: local histogram
#pragma unroll
  for (int it = 0; it < 16; ++it) {
    int i = n0 + it * 256 + t;
    if (i < NNZ) atomicAdd(&hist[rop[i] >> 9], 1);
  }
  __syncthreads();
  // local exclusive scan of hist (256-wide Hillis-Steele covers NBK=98)
  int v = (t < NBK) ? hist[t] : 0;
  sh[t] = v;
  __syncthreads();
#pragma unroll
  for (int off = 1; off < 256; off <<= 1) {
    int tmp = (t >= off) ? sh[t - off] : 0;
    __syncthreads();
    sh[t] += tmp;
    __syncthreads();
  }
  if (t < NBK) {
    int ex = sh[t] - v;
    lstart[t] = ex;
    cur[t] = ex;
    gbase[t] = op * NNZ + bs[op * NBK + t] +
               hoff[((size_t)op * CHUNKS + c) * NBK + t];
  }
  __syncthreads();
  // pass 2: scatter into LDS staging in bucket order
#pragma unroll
  for (int it = 0; it < 16; ++it) {
    int i = n0 + it * 256 + t;
    if (i < NNZ) {
      int r = rop[i];
      int b = r >> 9;
      int p = atomicAdd(&cur[b], 1);
      uint cv = ((uint)f2bf(vop[i]) << 16) | (uint)cop[i];
      stage[p] = ((u64)cv << 32) | (uint)(b << 9) | (uint)(r & 511);
    }
  }
  __syncthreads();
  // write-out: sequential, coalesced
  for (int q = t; q < nthis; q += 256) {
    u64 w = stage[q];
    int b = (int)((w >> 9) & 127u);
    part[(size_t)gbase[b] + (q - lstart[b])] = w;
  }
}

// B4: per (bucket,op): LDS slot counters -> ELL + cnt (fully written, no memset)
__global__ __launch_bounds__(256) void b4_build(const u64* __restrict__ part,
                                                const int* __restrict__ bs,
                                                const int* __restrict__ tot,
                                                uint* __restrict__ ell,
                                                int* __restrict__ cnt) {
  const int op = blockIdx.y, b = blockIdx.x;
  __shared__ int c[512];
  for (int t = threadIdx.x; t < 512; t += 256) c[t] = 0;
  __syncthreads();
  const int s = bs[op * NBK + b], n = tot[op * NBK + b];
  const u64* seg = part + (size_t)op * NNZ + s;
  uint* ellb = ell + (size_t)op * N_NODES * ELL_C + (size_t)b * 512 * ELL_C;
  for (int i = threadIdx.x; i < n; i += 256) {
    u64 w = seg[i];
    int rl = (int)(w & 0x1FFu);
    int p = atomicAdd(&c[rl], 1);
    if (p < ELL_C) ellb[rl * ELL_C + p] = (uint)(w >> 32);
  }
  __syncthreads();
  const int nrow = min(512, N_NODES - b * 512);
  int* cb = cnt + (size_t)op * N_NODES + b * 512;
  for (int t = threadIdx.x; t < nrow; t += 256) cb[t] = c[t];
}

// -------- SpMM: feature-sliced (slice = blockIdx&7 -> XCD-local L2 gathers) ----
// H layout: [slice(8)][row(50000)][32 bytes]. 8-lane group per (row, slice).
#ifdef HAS_FP8_CVT
#define DEC4(g, lo, hi)                                                   \
  lo = __builtin_amdgcn_cvt_pk_f32_fp8((g), false);                       \
  hi = __builtin_amdgcn_cvt_pk_f32_fp8((g), true);
#else
#define DEC4(g, lo, hi)                                                   \
  lo[0] = fp8_dec1((g) & 0xFFu); lo[1] = fp8_dec1(((g) >> 8) & 0xFFu);    \
  hi[0] = fp8_dec1(((g) >> 16) & 0xFFu); hi[1] = fp8_dec1((g) >> 24);
#endif

#define PROC(cv)                                                          \
  {                                                                       \
    uint c_ = (cv) & 0xFFFFu;                                             \
    float v_ = __uint_as_float((cv) & 0xFFFF0000u);                       \
    uint g = *(const uint*)(hs + (size_t)c_ * 32);                        \
    f32x2 glo, ghi;                                                       \
    DEC4(g, glo, ghi);                                                    \
    a0 = fmaf(v_, glo[0], a0);                                            \
    a1 = fmaf(v_, glo[1], a1);                                            \
    a2 = fmaf(v_, ghi[0], a2);                                            \
    a3 = fmaf(v_, ghi[1], a3);                                            \
  }

template <int MODE>
__global__ __launch_bounds__(256) void spmm_k(const int* __restrict__ cnt,
                                              const uint* __restrict__ ell,
                                              const u8* __restrict__ hin,
                                              void* __restrict__ out,
                                              const float* __restrict__ filt,
                                              const float* __restrict__ bias,
                                              float m1, float m2) {
  const int slice = blockIdx.x & 7;
  const int lane = threadIdx.x & 63;
  const int w = threadIdx.x >> 6;
  const int r = (blockIdx.x >> 3) * 32 + w * 8 + (lane >> 3);
  const int word = lane & 7;
  if (r >= N_NODES) return;
  int e = cnt[r];
  e = e < ELL_C ? e : ELL_C;
  const uint* __restrict__ row = ell + (size_t)r * ELL_C;
  const u8* __restrict__ hs = hin + (size_t)slice * N32 + word * 4;
  float a0 = 0.f, a1 = 0.f, a2 = 0.f, a3 = 0.f;
  int j = 0;
  for (; j + 8 <= e; j += 8) {
    uint4 q0 = *(const uint4*)(row + j);
    uint4 q1 = *(const uint4*)(row + j + 4);
    PROC(q0.x); PROC(q0.y); PROC(q0.z); PROC(q0.w);
    PROC(q1.x); PROC(q1.y); PROC(q1.z); PROC(q1.w);
  }
  for (; j + 4 <= e; j += 4) {
    uint4 q = *(const uint4*)(row + j);
    PROC(q.x); PROC(q.y); PROC(q.z); PROC(q.w);
  }
  for (; j < e; ++j) {
    uint cv = row[j];
    PROC(cv);
  }
  if (MODE == 0) {
    uint o = fp8_enc4(a0 * m1, a1 * m1, a2 * m1, a3 * m1);
    *(uint*)((u8*)out + (size_t)slice * N32 + (size_t)r * 32 + word * 4) = o;
  } else if (MODE == 1) {
    float fl = filt[r] * m2;
    uint o = fp8_enc4(shrinkf(a0 * m1) * fl, shrinkf(a1 * m1) * fl,
                      shrinkf(a2 * m1) * fl, shrinkf(a3 * m1) * fl);
    *(uint*)((u8*)out + (size_t)slice * N32 + (size_t)r * 32 + word * 4) = o;
  } else {
    float4 b = *(const float4*)(bias + slice * 32 + word * 4);
    float4 o;
    o.x = fmaf(a0, m1, b.x); o.y = fmaf(a1, m1, b.y);
    o.z = fmaf(a2, m1, b.z); o.w = fmaf(a3, m1, b.w);
    *(float4*)((float*)out + (size_t)r * F + slice * 32 + word * 4) = o;
  }
}

extern "C" void kernel_launch(void* const* d_in, const int* in_sizes, int n_in,
                              void* d_out, int out_size, void* d_ws, size_t ws_size,
                              hipStream_t stream) {
  const float* X = (const float*)d_in[0];
  const float* W = (const float*)d_in[1];
  const float* filt = (const float*)d_in[2];
  const float* bias = (const float*)d_in[3];
  const float* dvals = (const float*)d_in[4];
  const int* drows = (const int*)d_in[5];
  const int* dcols = (const int*)d_in[6];

  char* p = (char*)d_ws;
  auto alloc = [&](size_t bytes) {
    char* q = p;
    p += (bytes + 255) & ~(size_t)255;
    return q;
  };
  u8* hA = (u8*)alloc((size_t)N_NODES * F);
  u8* hB = (u8*)alloc((size_t)N_NODES * F);
  u16* Wb = (u16*)alloc((size_t)F * F * 2);
  int* cnt = (int*)alloc((size_t)L_OPS * N_NODES * 4);
  uint* ell = (uint*)alloc((size_t)L_OPS * N_NODES * ELL_C * 4);
  u64* part = (u64*)alloc((size_t)L_OPS * NNZ * 8);
  int* hoff = (int*)alloc((size_t)L_OPS * CHUNKS * NBK * 4);
  int* tot = (int*)alloc((size_t)L_OPS * NBK * 4);
  int* bs = (int*)alloc((size_t)L_OPS * NBK * 4);

  // ---- ELL build: radix buckets, LDS atomics only ----
  b1_hist<<<dim3(CHUNKS, L_OPS), 256, 0, stream>>>(drows, hoff);
  b2a_scan<<<dim3(NBK, L_OPS), 512, 0, stream>>>(hoff, tot);
  b2b_base<<<L_OPS, 128, 0, stream>>>(tot, bs);
  b3_scatter<<<dim3(CHUNKS, L_OPS), 256, 0, stream>>>(drows, dcols, dvals,
                                                      hoff, bs, part);
  b4_build<<<dim3(NBK, L_OPS), 256, 0, stream>>>(part, bs, tot, ell, cnt);

  // ---- H = X @ W (fp8 sliced layout, scale 2^4) ----
  wprep_k<<<64, 256, 0, stream>>>(W, Wb);
  gemm_mfma<<<1024, 256, 0, stream>>>(X, Wb, hA);

  auto sp = [&](int op, const u8* in, void* out, int mode, float m1, float m2) {
    const int* co = cnt + (size_t)op * N_NODES;
    const uint* eo = ell + (size_t)op * N_NODES * ELL_C;
    dim3 g(((N_NODES + 31) / 32) * 8);
    if (mode == 0)
      spmm_k<0><<<g, 256, 0, stream>>>(co, eo, in, out, filt, bias, m1, m2);
    else if (mode == 1)
      spmm_k<1><<<g, 256, 0, stream>>>(co, eo, in, out, filt, bias, m1, m2);
    else
      spmm_k<2><<<g, 256, 0, stream>>>(co, eo, in, out, filt, bias, m1, m2);
  };

  // scales: H=2^4 -> 2^6 -> 2^8 -> 2^10 -(shrink/filt)-> 2^13 -> 2^15 -> 2^17
  sp(0, hA, hB, 0, 4.f, 0.f);
  sp(1, hB, hA, 0, 4.f, 0.f);
  sp(2, hA, hB, 0, 4.f, 0.f);
  sp(3, hB, hA, 1, 0x1.0p-10f, 0x1.0p+13f);
  // reconstruction: ops 1,2,3 (+bias on final, f32 out)
  sp(1, hA, hB, 0, 4.f, 0.f);
  sp(2, hB, hA, 0, 4.f, 0.f);
  sp(3, hA, d_out, 2, 0x1.0p-17f, 0.f);
}

// Round 9
// 318.948 us; speedup vs baseline: 1.1908x; 1.1908x over previous
//
#include <hip/hip_runtime.h>
#include <hip/hip_bf16.h>

#define N_NODES 50000
#define NNZ 800000
#define F 256
#define L_OPS 4
#define ELL_C 64     // max row degree; Poisson(16) => P(deg>=64) ~ 1e-19 per row
#define RTILES 3125  // 50000 / 16 row tiles
#define NBK 98       // buckets of 512 rows
#define CHUNK 4096
#define CHUNKS 196   // ceil(NNZ / 4096)

typedef unsigned int uint;
typedef unsigned short u16;
typedef unsigned char u8;
typedef unsigned long long u64;
typedef __attribute__((ext_vector_type(8))) short bf16x8;
typedef __attribute__((ext_vector_type(4))) float f32x4;
typedef __attribute__((ext_vector_type(2))) float f32x2;

#if defined(__has_builtin)
#if __has_builtin(__builtin_amdgcn_cvt_pk_f32_fp8) && \
    __has_builtin(__builtin_amdgcn_cvt_pk_fp8_f32)
#define HAS_FP8_CVT 1
#endif
#endif

__device__ inline u16 f2bf(float f) {
  return __bfloat16_as_ushort(__float2bfloat16(f));  // hw v_cvt (RNE)
}
__device__ inline float shrinkf(float f) {
  float t = fabsf(f) - 1e-4f;
  t = t > 0.f ? t : 0.f;
  return copysignf(t, f);
}

// ---- fp8 e4m3 (OCP) helpers ----
__device__ inline uint fp8_enc1(float f) {
#ifdef HAS_FP8_CVT
  return (uint)__builtin_amdgcn_cvt_pk_fp8_f32(f, 0.f, 0, false) & 0xFFu;
#else
  float y = f * 0x1.0p-120f;
  uint b = __float_as_uint(y);
  uint s = (b >> 24) & 0x80u;
  b &= 0x7FFFFFFFu;
  uint r = b + 0x7FFFFu + ((b >> 20) & 1u);
  return s | ((r >> 20) & 0x7Fu);
#endif
}
__device__ inline uint fp8_enc4(float a, float b, float c, float d) {
#ifdef HAS_FP8_CVT
  uint w = (uint)__builtin_amdgcn_cvt_pk_fp8_f32(a, b, 0, false);
  w = (uint)__builtin_amdgcn_cvt_pk_fp8_f32(c, d, w, true);
  return w;
#else
  return fp8_enc1(a) | (fp8_enc1(b) << 8) | (fp8_enc1(c) << 16) |
         (fp8_enc1(d) << 24);
#endif
}
__device__ inline float fp8_dec1(uint b) {
  uint u = ((b & 0x80u) << 24) | ((b & 0x7Fu) << 20);
  return __uint_as_float(u) * 0x1.0p+120f;
}

// ---------------- W prep ----------------
__global__ __launch_bounds__(256) void wprep_k(const float* __restrict__ W,
                                               u16* __restrict__ Wb) {
  int T = blockIdx.x * 256 + threadIdx.x;
  if (T >= 16 * 8 * 64) return;
  int lane = T & 63;
  int ks = (T >> 6) & 7;
  int ct = T >> 9;
  int k0 = ks * 32 + (lane >> 4) * 8;
  int n = ct * 16 + (lane & 15);
  u16* o = Wb + (size_t)T * 8;
#pragma unroll
  for (int j = 0; j < 8; ++j) o[j] = f2bf(W[(size_t)(k0 + j) * F + n]);
}

// ---------------- GEMM: H(fp8, scale 2^4) = X @ W via MFMA ----------------
__global__ __launch_bounds__(256) void gemm_mfma(const float* __restrict__ X,
                                                 const u16* __restrict__ Wb,
                                                 u8* __restrict__ H) {
  const int w = threadIdx.x >> 6, lane = threadIdx.x & 63;
  const int lr = lane & 15, kg = lane >> 4;
  const int ct0 = w * 4;

  bf16x8 b[4][8];
#pragma unroll
  for (int c = 0; c < 4; ++c)
#pragma unroll
    for (int ks = 0; ks < 8; ++ks)
      b[c][ks] = *(const bf16x8*)(Wb + ((size_t)((ct0 + c) * 8 + ks) * 64 + lane) * 8);

  for (int tile = blockIdx.x; tile < RTILES; tile += gridDim.x) {
    const int rb = tile * 16;
    const float* xp = X + (size_t)(rb + lr) * F + kg * 8;
    f32x4 acc[4];
#pragma unroll
    for (int c = 0; c < 4; ++c) acc[c] = (f32x4){0.f, 0.f, 0.f, 0.f};
#pragma unroll
    for (int ks = 0; ks < 8; ++ks) {
      float4 x0 = *(const float4*)(xp + ks * 32);
      float4 x1 = *(const float4*)(xp + ks * 32 + 4);
      bf16x8 a;
      a[0] = (short)f2bf(x0.x); a[1] = (short)f2bf(x0.y);
      a[2] = (short)f2bf(x0.z); a[3] = (short)f2bf(x0.w);
      a[4] = (short)f2bf(x1.x); a[5] = (short)f2bf(x1.y);
      a[6] = (short)f2bf(x1.z); a[7] = (short)f2bf(x1.w);
#pragma unroll
      for (int c = 0; c < 4; ++c)
        acc[c] = __builtin_amdgcn_mfma_f32_16x16x32_bf16(a, b[c][ks], acc[c], 0, 0, 0);
    }
    const int r0 = rb + kg * 4;
#pragma unroll
    for (int c = 0; c < 4; ++c)
#pragma unroll
      for (int reg = 0; reg < 4; ++reg)
        H[(size_t)(r0 + reg) * F + (ct0 + c) * 16 + lr] =
            (u8)fp8_enc1(acc[c][reg] * 16.f);
  }
}

// ============ ELL build via radix buckets — NO global atomics ============
// B1: per-chunk LDS histogram over NBK buckets (512 rows each)
__global__ __launch_bounds__(256) void b1_hist(const int* __restrict__ rows,
                                               int* __restrict__ hoff) {
  const int op = blockIdx.y, c = blockIdx.x;
  __shared__ int h[NBK];
  for (int t = threadIdx.x; t < NBK; t += 256) h[t] = 0;
  __syncthreads();
  const int* rop = rows + (size_t)op * NNZ;
  const int base = c * CHUNK + threadIdx.x;
#pragma unroll
  for (int it = 0; it < 16; ++it) {
    int i = base + it * 256;
    if (i < NNZ) atomicAdd(&h[rop[i] >> 9], 1);
  }
  __syncthreads();
  for (int t = threadIdx.x; t < NBK; t += 256)
    hoff[((size_t)op * CHUNKS + c) * NBK + t] = h[t];
}

// B2a: per (op,bucket): exclusive scan over chunks (in place) + bucket total
__global__ __launch_bounds__(512) void b2a_scan(int* __restrict__ hoff,
                                                int* __restrict__ tot) {
  const int op = blockIdx.y, b = blockIdx.x, t = threadIdx.x;
  __shared__ int sh[512];
  int v = (t < CHUNKS) ? hoff[((size_t)op * CHUNKS + t) * NBK + b] : 0;
  sh[t] = v;
  __syncthreads();
#pragma unroll
  for (int off = 1; off < 512; off <<= 1) {
    int tmp = (t >= off) ? sh[t - off] : 0;
    __syncthreads();
    sh[t] += tmp;
    __syncthreads();
  }
  if (t < CHUNKS) hoff[((size_t)op * CHUNKS + t) * NBK + b] = sh[t] - v;
  if (t == 511) tot[op * NBK + b] = sh[511];
}

// B2b: per op: exclusive scan of bucket totals -> bases
__global__ __launch_bounds__(128) void b2b_base(const int* __restrict__ tot,
                                                int* __restrict__ bs) {
  const int op = blockIdx.x, t = threadIdx.x;
  __shared__ int sh[128];
  int v = (t < NBK) ? tot[op * NBK + t] : 0;
  sh[t] = v;
  __syncthreads();
#pragma unroll
  for (int off = 1; off < 128; off <<= 1) {
    int tmp = (t >= off) ? sh[t - off] : 0;
    __syncthreads();
    sh[t] += tmp;
    __syncthreads();
  }
  if (t < NBK) bs[op * NBK + t] = sh[t] - v;
}

// B3: in-LDS counting sort per 4096-chunk, then coalesced sequential write-out.
__global__ __launch_bounds__(256) void b3_scatter(const int* __restrict__ rows,
                                                  const int* __restrict__ cols,
                                                  const float* __restrict__ vals,
                                                  const int* __restrict__ hoff,
                                                  const int* __restrict__ bs,
                                                  u64* __restrict__ part) {
  const int op = blockIdx.y, c = blockIdx.x;
  __shared__ int hist[NBK];
  __shared__ int lstart[NBK];
  __shared__ int gbase[NBK];
  __shared__ int cur[NBK];
  __shared__ int sh[256];
  __shared__ u64 stage[CHUNK];
  const int t = threadIdx.x;
  for (int k = t; k < NBK; k += 256) hist[k] = 0;
  __syncthreads();
  const int* rop = rows + (size_t)op * NNZ;
  const int* cop = cols + (size_t)op * NNZ;
  const float* vop = vals + (size_t)op * NNZ;
  const int n0 = c * CHUNK;
  const int nthis = min(CHUNK, NNZ - n0);
#pragma unroll
  for (int it = 0; it < 16; ++it) {
    int i = n0 + it * 256 + t;
    if (i < NNZ) atomicAdd(&hist[rop[i] >> 9], 1);
  }
  __syncthreads();
  int v = (t < NBK) ? hist[t] : 0;
  sh[t] = v;
  __syncthreads();
#pragma unroll
  for (int off = 1; off < 256; off <<= 1) {
    int tmp = (t >= off) ? sh[t - off] : 0;
    __syncthreads();
    sh[t] += tmp;
    __syncthreads();
  }
  if (t < NBK) {
    int ex = sh[t] - v;
    lstart[t] = ex;
    cur[t] = ex;
    gbase[t] = op * NNZ + bs[op * NBK + t] +
               hoff[((size_t)op * CHUNKS + c) * NBK + t];
  }
  __syncthreads();
#pragma unroll
  for (int it = 0; it < 16; ++it) {
    int i = n0 + it * 256 + t;
    if (i < NNZ) {
      int r = rop[i];
      int b = r >> 9;
      int p = atomicAdd(&cur[b], 1);
      uint cv = ((uint)f2bf(vop[i]) << 16) | (uint)cop[i];
      stage[p] = ((u64)cv << 32) | (uint)(b << 9) | (uint)(r & 511);
    }
  }
  __syncthreads();
  for (int q = t; q < nthis; q += 256) {
    u64 w = stage[q];
    int b = (int)((w >> 9) & 127u);
    part[(size_t)gbase[b] + (q - lstart[b])] = w;
  }
}

// B4: per (bucket,op): LDS slot counters -> ELL + cnt (fully written, no memset)
__global__ __launch_bounds__(256) void b4_build(const u64* __restrict__ part,
                                                const int* __restrict__ bs,
                                                const int* __restrict__ tot,
                                                uint* __restrict__ ell,
                                                int* __restrict__ cnt) {
  const int op = blockIdx.y, b = blockIdx.x;
  __shared__ int c[512];
  for (int t = threadIdx.x; t < 512; t += 256) c[t] = 0;
  __syncthreads();
  const int s = bs[op * NBK + b], n = tot[op * NBK + b];
  const u64* seg = part + (size_t)op * NNZ + s;
  uint* ellb = ell + (size_t)op * N_NODES * ELL_C + (size_t)b * 512 * ELL_C;
  for (int i = threadIdx.x; i < n; i += 256) {
    u64 w = seg[i];
    int rl = (int)(w & 0x1FFu);
    int p = atomicAdd(&c[rl], 1);
    if (p < ELL_C) ellb[rl * ELL_C + p] = (uint)(w >> 32);
  }
  __syncthreads();
  const int nrow = min(512, N_NODES - b * 512);
  int* cb = cnt + (size_t)op * N_NODES + b * 512;
  for (int t = threadIdx.x; t < nrow; t += 256) cb[t] = c[t];
}

// ---------------- SpMM (pull, ELL, 1 wave per row, fp8 gathers) ---------------
#ifdef HAS_FP8_CVT
#define DEC4(g, lo, hi)                                                   \
  lo = __builtin_amdgcn_cvt_pk_f32_fp8((g), false);                       \
  hi = __builtin_amdgcn_cvt_pk_f32_fp8((g), true);
#else
#define DEC4(g, lo, hi)                                                   \
  lo[0] = fp8_dec1((g) & 0xFFu); lo[1] = fp8_dec1(((g) >> 8) & 0xFFu);    \
  hi[0] = fp8_dec1(((g) >> 16) & 0xFFu); hi[1] = fp8_dec1((g) >> 24);
#endif

#define PROC(cv)                                                          \
  {                                                                       \
    uint c_ = (cv) & 0xFFFFu;                                             \
    float v_ = __uint_as_float((cv) & 0xFFFF0000u);                       \
    uint g = *(const uint*)(hinL + (size_t)c_ * F);                       \
    f32x2 glo, ghi;                                                       \
    DEC4(g, glo, ghi);                                                    \
    a0 = fmaf(v_, glo[0], a0);                                            \
    a1 = fmaf(v_, glo[1], a1);                                            \
    a2 = fmaf(v_, ghi[0], a2);                                            \
    a3 = fmaf(v_, ghi[1], a3);                                            \
  }

template <int MODE>
__global__ __launch_bounds__(256) void spmm_k(const int* __restrict__ cnt,
                                              const uint* __restrict__ ell,
                                              const u8* __restrict__ hin,
                                              void* __restrict__ out,
                                              const float* __restrict__ filt,
                                              const float* __restrict__ bias,
                                              float m1, float m2) {
  const int lane = threadIdx.x & 63;
  const int r = blockIdx.x * 4 + (threadIdx.x >> 6);
  if (r >= N_NODES) return;
  int e = cnt[r];
  e = e < ELL_C ? e : ELL_C;
  const uint* __restrict__ row = ell + (size_t)r * ELL_C;
  const u8* __restrict__ hinL = hin + lane * 4;
  float a0 = 0.f, a1 = 0.f, a2 = 0.f, a3 = 0.f;
  int j = 0;
  for (; j + 8 <= e; j += 8) {
    uint4 q0 = *(const uint4*)(row + j);
    uint4 q1 = *(const uint4*)(row + j + 4);
    PROC(q0.x); PROC(q0.y); PROC(q0.z); PROC(q0.w);
    PROC(q1.x); PROC(q1.y); PROC(q1.z); PROC(q1.w);
  }
  for (; j + 4 <= e; j += 4) {
    uint4 q = *(const uint4*)(row + j);
    PROC(q.x); PROC(q.y); PROC(q.z); PROC(q.w);
  }
  for (; j < e; ++j) {
    uint cv = row[j];
    PROC(cv);
  }
  if (MODE == 0) {
    uint w = fp8_enc4(a0 * m1, a1 * m1, a2 * m1, a3 * m1);
    *(uint*)((u8*)out + (size_t)r * F + lane * 4) = w;
  } else if (MODE == 1) {
    float fl = filt[r] * m2;
    uint w = fp8_enc4(shrinkf(a0 * m1) * fl, shrinkf(a1 * m1) * fl,
                      shrinkf(a2 * m1) * fl, shrinkf(a3 * m1) * fl);
    *(uint*)((u8*)out + (size_t)r * F + lane * 4) = w;
  } else {
    float4 b = *(const float4*)(bias + lane * 4);
    float4 o;
    o.x = fmaf(a0, m1, b.x); o.y = fmaf(a1, m1, b.y);
    o.z = fmaf(a2, m1, b.z); o.w = fmaf(a3, m1, b.w);
    *(float4*)((float*)out + (size_t)r * F + lane * 4) = o;
  }
}

extern "C" void kernel_launch(void* const* d_in, const int* in_sizes, int n_in,
                              void* d_out, int out_size, void* d_ws, size_t ws_size,
                              hipStream_t stream) {
  const float* X = (const float*)d_in[0];
  const float* W = (const float*)d_in[1];
  const float* filt = (const float*)d_in[2];
  const float* bias = (const float*)d_in[3];
  const float* dvals = (const float*)d_in[4];
  const int* drows = (const int*)d_in[5];
  const int* dcols = (const int*)d_in[6];

  char* p = (char*)d_ws;
  auto alloc = [&](size_t bytes) {
    char* q = p;
    p += (bytes + 255) & ~(size_t)255;
    return q;
  };
  u8* hA = (u8*)alloc((size_t)N_NODES * F);
  u8* hB = (u8*)alloc((size_t)N_NODES * F);
  u16* Wb = (u16*)alloc((size_t)F * F * 2);
  int* cnt = (int*)alloc((size_t)L_OPS * N_NODES * 4);
  uint* ell = (uint*)alloc((size_t)L_OPS * N_NODES * ELL_C * 4);
  u64* part = (u64*)alloc((size_t)L_OPS * NNZ * 8);
  int* hoff = (int*)alloc((size_t)L_OPS * CHUNKS * NBK * 4);
  int* tot = (int*)alloc((size_t)L_OPS * NBK * 4);
  int* bs = (int*)alloc((size_t)L_OPS * NBK * 4);

  // ---- ELL build: radix buckets, LDS atomics only ----
  b1_hist<<<dim3(CHUNKS, L_OPS), 256, 0, stream>>>(drows, hoff);
  b2a_scan<<<dim3(NBK, L_OPS), 512, 0, stream>>>(hoff, tot);
  b2b_base<<<L_OPS, 128, 0, stream>>>(tot, bs);
  b3_scatter<<<dim3(CHUNKS, L_OPS), 256, 0, stream>>>(drows, dcols, dvals,
                                                      hoff, bs, part);
  b4_build<<<dim3(NBK, L_OPS), 256, 0, stream>>>(part, bs, tot, ell, cnt);

  // ---- H = X @ W (fp8 out, scale 2^4) ----
  wprep_k<<<64, 256, 0, stream>>>(W, Wb);
  gemm_mfma<<<1024, 256, 0, stream>>>(X, Wb, hA);

  auto sp = [&](int op, const u8* in, void* out, int mode, float m1, float m2) {
    const int* co = cnt + (size_t)op * N_NODES;
    const uint* eo = ell + (size_t)op * N_NODES * ELL_C;
    dim3 g((N_NODES + 3) / 4);
    if (mode == 0)
      spmm_k<0><<<g, 256, 0, stream>>>(co, eo, in, out, filt, bias, m1, m2);
    else if (mode == 1)
      spmm_k<1><<<g, 256, 0, stream>>>(co, eo, in, out, filt, bias, m1, m2);
    else
      spmm_k<2><<<g, 256, 0, stream>>>(co, eo, in, out, filt, bias, m1, m2);
  };

  // scales: H=2^4 -> 2^6 -> 2^8 -> 2^10 -(shrink/filt)-> 2^13 -> 2^15 -> 2^17
  sp(0, hA, hB, 0, 4.f, 0.f);
  sp(1, hB, hA, 0, 4.f, 0.f);
  sp(2, hA, hB, 0, 4.f, 0.f);
  sp(3, hB, hA, 1, 0x1.0p-10f, 0x1.0p+13f);
  // reconstruction: ops 1,2,3 (+bias on final, f32 out)
  sp(1, hA, hB, 0, 4.f, 0.f);
  sp(2, hB, hA, 0, 4.f, 0.f);
  sp(3, hA, d_out, 2, 0x1.0p-17f, 0.f);
}

// Round 10
// 314.733 us; speedup vs baseline: 1.2067x; 1.0134x over previous
//
#include <hip/hip_runtime.h>
#include <hip/hip_bf16.h>

#define N_NODES 50000
#define NNZ 800000
#define F 256
#define L_OPS 4
#define ELL_C 64     // max row degree; Poisson(16) => P(deg>=64) ~ 1e-19 per row
#define RTILES 3125  // 50000 / 16 row tiles
#define NBK 98       // buckets of 512 rows
#define CHUNK 4096
#define CHUNKS 196   // ceil(NNZ / 4096)

typedef unsigned int uint;
typedef unsigned short u16;
typedef unsigned char u8;
typedef unsigned long long u64;
typedef __attribute__((ext_vector_type(8))) short bf16x8;
typedef __attribute__((ext_vector_type(4))) float f32x4;
typedef __attribute__((ext_vector_type(2))) float f32x2;

#if defined(__has_builtin)
#if __has_builtin(__builtin_amdgcn_cvt_pk_f32_fp8) && \
    __has_builtin(__builtin_amdgcn_cvt_pk_fp8_f32)
#define HAS_FP8_CVT 1
#endif
#endif

__device__ inline u16 f2bf(float f) {
  return __bfloat16_as_ushort(__float2bfloat16(f));  // hw v_cvt (RNE)
}
__device__ inline float shrinkf(float f) {
  float t = fabsf(f) - 1e-4f;
  t = t > 0.f ? t : 0.f;
  return copysignf(t, f);
}

// ---- fp8 e4m3 (OCP) helpers ----
__device__ inline uint fp8_enc1(float f) {
#ifdef HAS_FP8_CVT
  return (uint)__builtin_amdgcn_cvt_pk_fp8_f32(f, 0.f, 0, false) & 0xFFu;
#else
  float y = f * 0x1.0p-120f;
  uint b = __float_as_uint(y);
  uint s = (b >> 24) & 0x80u;
  b &= 0x7FFFFFFFu;
  uint r = b + 0x7FFFFu + ((b >> 20) & 1u);
  return s | ((r >> 20) & 0x7Fu);
#endif
}
__device__ inline uint fp8_enc4(float a, float b, float c, float d) {
#ifdef HAS_FP8_CVT
  uint w = (uint)__builtin_amdgcn_cvt_pk_fp8_f32(a, b, 0, false);
  w = (uint)__builtin_amdgcn_cvt_pk_fp8_f32(c, d, w, true);
  return w;
#else
  return fp8_enc1(a) | (fp8_enc1(b) << 8) | (fp8_enc1(c) << 16) |
         (fp8_enc1(d) << 24);
#endif
}
__device__ inline float fp8_dec1(uint b) {
  uint u = ((b & 0x80u) << 24) | ((b & 0x7Fu) << 20);
  return __uint_as_float(u) * 0x1.0p+120f;
}

// ---------------- W prep ----------------
__global__ __launch_bounds__(256) void wprep_k(const float* __restrict__ W,
                                               u16* __restrict__ Wb) {
  int T = blockIdx.x * 256 + threadIdx.x;
  if (T >= 16 * 8 * 64) return;
  int lane = T & 63;
  int ks = (T >> 6) & 7;
  int ct = T >> 9;
  int k0 = ks * 32 + (lane >> 4) * 8;
  int n = ct * 16 + (lane & 15);
  u16* o = Wb + (size_t)T * 8;
#pragma unroll
  for (int j = 0; j < 8; ++j) o[j] = f2bf(W[(size_t)(k0 + j) * F + n]);
}

// ---------------- GEMM: H(fp8, scale 2^4) = X @ W via MFMA ----------------
// __launch_bounds__(256, 2): 2 waves/SIMD -> 256 VGPR budget so B-frags (128)
// + full X tile (64) + acc stay register-resident (R9's VGPR=120 showed the
// compiler was evicting B at the default 4-wave target -> L2 reload latency).
__global__ __launch_bounds__(256, 2) void gemm_mfma(const float* __restrict__ X,
                                                    const u16* __restrict__ Wb,
                                                    u8* __restrict__ H) {
  const int w = threadIdx.x >> 6, lane = threadIdx.x & 63;
  const int lr = lane & 15, kg = lane >> 4;
  const int ct0 = w * 4;

  bf16x8 b[4][8];
#pragma unroll
  for (int c = 0; c < 4; ++c)
#pragma unroll
    for (int ks = 0; ks < 8; ++ks)
      b[c][ks] = *(const bf16x8*)(Wb + ((size_t)((ct0 + c) * 8 + ks) * 64 + lane) * 8);

  for (int tile = blockIdx.x; tile < RTILES; tile += gridDim.x) {
    const int rb = tile * 16;
    const float* xp = X + (size_t)(rb + lr) * F + kg * 8;
    // batch all 16 tile loads -> 16 outstanding VMEM ops, then compute
    float4 xv[16];
#pragma unroll
    for (int ks = 0; ks < 8; ++ks) {
      xv[2 * ks]     = *(const float4*)(xp + ks * 32);
      xv[2 * ks + 1] = *(const float4*)(xp + ks * 32 + 4);
    }
    f32x4 acc[4];
#pragma unroll
    for (int c = 0; c < 4; ++c) acc[c] = (f32x4){0.f, 0.f, 0.f, 0.f};
#pragma unroll
    for (int ks = 0; ks < 8; ++ks) {
      float4 x0 = xv[2 * ks], x1 = xv[2 * ks + 1];
      bf16x8 a;
      a[0] = (short)f2bf(x0.x); a[1] = (short)f2bf(x0.y);
      a[2] = (short)f2bf(x0.z); a[3] = (short)f2bf(x0.w);
      a[4] = (short)f2bf(x1.x); a[5] = (short)f2bf(x1.y);
      a[6] = (short)f2bf(x1.z); a[7] = (short)f2bf(x1.w);
#pragma unroll
      for (int c = 0; c < 4; ++c)
        acc[c] = __builtin_amdgcn_mfma_f32_16x16x32_bf16(a, b[c][ks], acc[c], 0, 0, 0);
    }
    const int r0 = rb + kg * 4;
#pragma unroll
    for (int c = 0; c < 4; ++c)
#pragma unroll
      for (int reg = 0; reg < 4; ++reg)
        H[(size_t)(r0 + reg) * F + (ct0 + c) * 16 + lr] =
            (u8)fp8_enc1(acc[c][reg] * 16.f);
  }
}

// ============ ELL build via radix buckets — NO global atomics ============
__global__ __launch_bounds__(256) void b1_hist(const int* __restrict__ rows,
                                               int* __restrict__ hoff) {
  const int op = blockIdx.y, c = blockIdx.x;
  __shared__ int h[NBK];
  for (int t = threadIdx.x; t < NBK; t += 256) h[t] = 0;
  __syncthreads();
  const int* rop = rows + (size_t)op * NNZ;
  const int base = c * CHUNK + threadIdx.x;
#pragma unroll
  for (int it = 0; it < 16; ++it) {
    int i = base + it * 256;
    if (i < NNZ) atomicAdd(&h[rop[i] >> 9], 1);
  }
  __syncthreads();
  for (int t = threadIdx.x; t < NBK; t += 256)
    hoff[((size_t)op * CHUNKS + c) * NBK + t] = h[t];
}

__global__ __launch_bounds__(512) void b2a_scan(int* __restrict__ hoff,
                                                int* __restrict__ tot) {
  const int op = blockIdx.y, b = blockIdx.x, t = threadIdx.x;
  __shared__ int sh[512];
  int v = (t < CHUNKS) ? hoff[((size_t)op * CHUNKS + t) * NBK + b] : 0;
  sh[t] = v;
  __syncthreads();
#pragma unroll
  for (int off = 1; off < 512; off <<= 1) {
    int tmp = (t >= off) ? sh[t - off] : 0;
    __syncthreads();
    sh[t] += tmp;
    __syncthreads();
  }
  if (t < CHUNKS) hoff[((size_t)op * CHUNKS + t) * NBK + b] = sh[t] - v;
  if (t == 511) tot[op * NBK + b] = sh[511];
}

__global__ __launch_bounds__(128) void b2b_base(const int* __restrict__ tot,
                                                int* __restrict__ bs) {
  const int op = blockIdx.x, t = threadIdx.x;
  __shared__ int sh[128];
  int v = (t < NBK) ? tot[op * NBK + t] : 0;
  sh[t] = v;
  __syncthreads();
#pragma unroll
  for (int off = 1; off < 128; off <<= 1) {
    int tmp = (t >= off) ? sh[t - off] : 0;
    __syncthreads();
    sh[t] += tmp;
    __syncthreads();
  }
  if (t < NBK) bs[op * NBK + t] = sh[t] - v;
}

__global__ __launch_bounds__(256) void b3_scatter(const int* __restrict__ rows,
                                                  const int* __restrict__ cols,
                                                  const float* __restrict__ vals,
                                                  const int* __restrict__ hoff,
                                                  const int* __restrict__ bs,
                                                  u64* __restrict__ part) {
  const int op = blockIdx.y, c = blockIdx.x;
  __shared__ int hist[NBK];
  __shared__ int lstart[NBK];
  __shared__ int gbase[NBK];
  __shared__ int cur[NBK];
  __shared__ int sh[256];
  __shared__ u64 stage[CHUNK];
  const int t = threadIdx.x;
  for (int k = t; k < NBK; k += 256) hist[k] = 0;
  __syncthreads();
  const int* rop = rows + (size_t)op * NNZ;
  const int* cop = cols + (size_t)op * NNZ;
  const float* vop = vals + (size_t)op * NNZ;
  const int n0 = c * CHUNK;
  const int nthis = min(CHUNK, NNZ - n0);
#pragma unroll
  for (int it = 0; it < 16; ++it) {
    int i = n0 + it * 256 + t;
    if (i < NNZ) atomicAdd(&hist[rop[i] >> 9], 1);
  }
  __syncthreads();
  int v = (t < NBK) ? hist[t] : 0;
  sh[t] = v;
  __syncthreads();
#pragma unroll
  for (int off = 1; off < 256; off <<= 1) {
    int tmp = (t >= off) ? sh[t - off] : 0;
    __syncthreads();
    sh[t] += tmp;
    __syncthreads();
  }
  if (t < NBK) {
    int ex = sh[t] - v;
    lstart[t] = ex;
    cur[t] = ex;
    gbase[t] = op * NNZ + bs[op * NBK + t] +
               hoff[((size_t)op * CHUNKS + c) * NBK + t];
  }
  __syncthreads();
#pragma unroll
  for (int it = 0; it < 16; ++it) {
    int i = n0 + it * 256 + t;
    if (i < NNZ) {
      int r = rop[i];
      int b = r >> 9;
      int p = atomicAdd(&cur[b], 1);
      uint cv = ((uint)f2bf(vop[i]) << 16) | (uint)cop[i];
      stage[p] = ((u64)cv << 32) | (uint)(b << 9) | (uint)(r & 511);
    }
  }
  __syncthreads();
  for (int q = t; q < nthis; q += 256) {
    u64 w = stage[q];
    int b = (int)((w >> 9) & 127u);
    part[(size_t)gbase[b] + (q - lstart[b])] = w;
  }
}

__global__ __launch_bounds__(256) void b4_build(const u64* __restrict__ part,
                                                const int* __restrict__ bs,
                                                const int* __restrict__ tot,
                                                uint* __restrict__ ell,
                                                int* __restrict__ cnt) {
  const int op = blockIdx.y, b = blockIdx.x;
  __shared__ int c[512];
  for (int t = threadIdx.x; t < 512; t += 256) c[t] = 0;
  __syncthreads();
  const int s = bs[op * NBK + b], n = tot[op * NBK + b];
  const u64* seg = part + (size_t)op * NNZ + s;
  uint* ellb = ell + (size_t)op * N_NODES * ELL_C + (size_t)b * 512 * ELL_C;
  for (int i = threadIdx.x; i < n; i += 256) {
    u64 w = seg[i];
    int rl = (int)(w & 0x1FFu);
    int p = atomicAdd(&c[rl], 1);
    if (p < ELL_C) ellb[rl * ELL_C + p] = (uint)(w >> 32);
  }
  __syncthreads();
  const int nrow = min(512, N_NODES - b * 512);
  int* cb = cnt + (size_t)op * N_NODES + b * 512;
  for (int t = threadIdx.x; t < nrow; t += 256) cb[t] = c[t];
}

// ---------------- SpMM (pull, ELL, 1 wave per row, fp8 gathers) ---------------
#ifdef HAS_FP8_CVT
#define DEC4(g, lo, hi)                                                   \
  lo = __builtin_amdgcn_cvt_pk_f32_fp8((g), false);                       \
  hi = __builtin_amdgcn_cvt_pk_f32_fp8((g), true);
#else
#define DEC4(g, lo, hi)                                                   \
  lo[0] = fp8_dec1((g) & 0xFFu); lo[1] = fp8_dec1(((g) >> 8) & 0xFFu);    \
  hi[0] = fp8_dec1(((g) >> 16) & 0xFFu); hi[1] = fp8_dec1((g) >> 24);
#endif

#define PROC(cv)                                                          \
  {                                                                       \
    uint c_ = (cv) & 0xFFFFu;                                             \
    float v_ = __uint_as_float((cv) & 0xFFFF0000u);                       \
    uint g = *(const uint*)(hinL + (size_t)c_ * F);                       \
    f32x2 glo, ghi;                                                       \
    DEC4(g, glo, ghi);                                                    \
    a0 = fmaf(v_, glo[0], a0);                                            \
    a1 = fmaf(v_, glo[1], a1);                                            \
    a2 = fmaf(v_, ghi[0], a2);                                            \
    a3 = fmaf(v_, ghi[1], a3);                                            \
  }

template <int MODE>
__global__ __launch_bounds__(256) void spmm_k(const int* __restrict__ cnt,
                                              const uint* __restrict__ ell,
                                              const u8* __restrict__ hin,
                                              void* __restrict__ out,
                                              const float* __restrict__ filt,
                                              const float* __restrict__ bias,
                                              float m1, float m2) {
  const int lane = threadIdx.x & 63;
  const int r = blockIdx.x * 4 + (threadIdx.x >> 6);
  if (r >= N_NODES) return;
  int e = cnt[r];
  e = e < ELL_C ? e : ELL_C;
  const uint* __restrict__ row = ell + (size_t)r * ELL_C;
  const u8* __restrict__ hinL = hin + lane * 4;
  float a0 = 0.f, a1 = 0.f, a2 = 0.f, a3 = 0.f;
  int j = 0;
  for (; j + 8 <= e; j += 8) {
    uint4 q0 = *(const uint4*)(row + j);
    uint4 q1 = *(const uint4*)(row + j + 4);
    PROC(q0.x); PROC(q0.y); PROC(q0.z); PROC(q0.w);
    PROC(q1.x); PROC(q1.y); PROC(q1.z); PROC(q1.w);
  }
  for (; j + 4 <= e; j += 4) {
    uint4 q = *(const uint4*)(row + j);
    PROC(q.x); PROC(q.y); PROC(q.z); PROC(q.w);
  }
  for (; j < e; ++j) {
    uint cv = row[j];
    PROC(cv);
  }
  if (MODE == 0) {
    uint w = fp8_enc4(a0 * m1, a1 * m1, a2 * m1, a3 * m1);
    *(uint*)((u8*)out + (size_t)r * F + lane * 4) = w;
  } else if (MODE == 1) {
    float fl = filt[r] * m2;
    uint w = fp8_enc4(shrinkf(a0 * m1) * fl, shrinkf(a1 * m1) * fl,
                      shrinkf(a2 * m1) * fl, shrinkf(a3 * m1) * fl);
    *(uint*)((u8*)out + (size_t)r * F + lane * 4) = w;
  } else {
    float4 b = *(const float4*)(bias + lane * 4);
    float4 o;
    o.x = fmaf(a0, m1, b.x); o.y = fmaf(a1, m1, b.y);
    o.z = fmaf(a2, m1, b.z); o.w = fmaf(a3, m1, b.w);
    *(float4*)((float*)out + (size_t)r * F + lane * 4) = o;
  }
}

extern "C" void kernel_launch(void* const* d_in, const int* in_sizes, int n_in,
                              void* d_out, int out_size, void* d_ws, size_t ws_size,
                              hipStream_t stream) {
  const float* X = (const float*)d_in[0];
  const float* W = (const float*)d_in[1];
  const float* filt = (const float*)d_in[2];
  const float* bias = (const float*)d_in[3];
  const float* dvals = (const float*)d_in[4];
  const int* drows = (const int*)d_in[5];
  const int* dcols = (const int*)d_in[6];

  char* p = (char*)d_ws;
  auto alloc = [&](size_t bytes) {
    char* q = p;
    p += (bytes + 255) & ~(size_t)255;
    return q;
  };
  u8* hA = (u8*)alloc((size_t)N_NODES * F);
  u8* hB = (u8*)alloc((size_t)N_NODES * F);
  u16* Wb = (u16*)alloc((size_t)F * F * 2);
  int* cnt = (int*)alloc((size_t)L_OPS * N_NODES * 4);
  uint* ell = (uint*)alloc((size_t)L_OPS * N_NODES * ELL_C * 4);
  u64* part = (u64*)alloc((size_t)L_OPS * NNZ * 8);
  int* hoff = (int*)alloc((size_t)L_OPS * CHUNKS * NBK * 4);
  int* tot = (int*)alloc((size_t)L_OPS * NBK * 4);
  int* bs = (int*)alloc((size_t)L_OPS * NBK * 4);

  // ---- ELL build: radix buckets, LDS atomics only ----
  b1_hist<<<dim3(CHUNKS, L_OPS), 256, 0, stream>>>(drows, hoff);
  b2a_scan<<<dim3(NBK, L_OPS), 512, 0, stream>>>(hoff, tot);
  b2b_base<<<L_OPS, 128, 0, stream>>>(tot, bs);
  b3_scatter<<<dim3(CHUNKS, L_OPS), 256, 0, stream>>>(drows, dcols, dvals,
                                                      hoff, bs, part);
  b4_build<<<dim3(NBK, L_OPS), 256, 0, stream>>>(part, bs, tot, ell, cnt);

  // ---- H = X @ W (fp8 out, scale 2^4) ----
  wprep_k<<<64, 256, 0, stream>>>(W, Wb);
  gemm_mfma<<<512, 256, 0, stream>>>(X, Wb, hA);

  auto sp = [&](int op, const u8* in, void* out, int mode, float m1, float m2) {
    const int* co = cnt + (size_t)op * N_NODES;
    const uint* eo = ell + (size_t)op * N_NODES * ELL_C;
    dim3 g((N_NODES + 3) / 4);
    if (mode == 0)
      spmm_k<0><<<g, 256, 0, stream>>>(co, eo, in, out, filt, bias, m1, m2);
    else if (mode == 1)
      spmm_k<1><<<g, 256, 0, stream>>>(co, eo, in, out, filt, bias, m1, m2);
    else
      spmm_k<2><<<g, 256, 0, stream>>>(co, eo, in, out, filt, bias, m1, m2);
  };

  // scales: H=2^4 -> 2^6 -> 2^8 -> 2^10 -(shrink/filt)-> 2^13 -> 2^15 -> 2^17
  sp(0, hA, hB, 0, 4.f, 0.f);
  sp(1, hB, hA, 0, 4.f, 0.f);
  sp(2, hA, hB, 0, 4.f, 0.f);
  sp(3, hB, hA, 1, 0x1.0p-10f, 0x1.0p+13f);
  // reconstruction: ops 1,2,3 (+bias on final, f32 out)
  sp(1, hA, hB, 0, 4.f, 0.f);
  sp(2, hB, hA, 0, 4.f, 0.f);
  sp(3, hA, d_out, 2, 0x1.0p-17f, 0.f);
}